// Round 12
// baseline (250.190 us; speedup 1.0000x reference)
//
#include <hip/hip_runtime.h>
#include <math.h>
#include <stdint.h>

#define NTOK  16384
#define NW6   (NTOK * 6)
#define D4    512              // float4 per full 2048-dim row
#define TPB   16               // tokens per block
#define NBLK  (NTOK / TPB)     // 1024 blocks
#define WDB   2304             // W double buffer: 2 x 18 rows x 64 f4 (36,864 B)
#define XSTR  65               // padded token stride in f4 (64 data + 1 pad)
#define XSLOT (4 * XSTR)       // one tile slot per wave: 4 tokens (260 f4)
#define XWV   (2 * XSLOT)      // 2-deep ring per wave (520 f4 = 8,320 B)
// smem: 2304 + 4*520 = 4384 f4 = 70,144 B (+64 B lcnt) -> 2 blocks/CU.

#define DOT4(a, b) ((a).x*(b).x + (a).y*(b).y + (a).z*(b).z + (a).w*(b).w)

// Async global->LDS DMA, 16 B per lane. LDS dest = wave-uniform base +
// lane*16 (contiguous); global src is per-lane. One instruction here reads
// 64 lanes x 16 B = 1 KB CONTIGUOUS from one row -> spans 4 x 256 B channel
// granules (the round-9 256 B-per-row shape put all of an instruction's
// requests on ONE granule -> channel serialization).
#define ASYNC_CP16(gsrc, ldst)                                              \
    __builtin_amdgcn_global_load_lds(                                       \
        (const __attribute__((address_space(1))) void*)(gsrc),              \
        (__attribute__((address_space(3))) void*)(ldst), 16, 0, 0)

// Counted vmem wait. "memory" clobber: compiler cannot move LDS reads or
// DMA issues across it.
template <int N>
__device__ __forceinline__ void waitv() {
    asm volatile("s_waitcnt vmcnt(%0)" :: "i"(N) : "memory");
}

// DPP row_shl sum-tree: lane i adds lane i+N (out-of-range -> 0). After 4
// steps lane 0 of each 16-lane row holds the full row sum. (Verified.)
template <int CTRL>
__device__ __forceinline__ float dpp_add(float v) {
    int moved = __builtin_amdgcn_update_dpp(0, __float_as_int(v),
                                            CTRL, 0xF, 0xF, true);
    return v + __int_as_float(moved);
}
__device__ __forceinline__ float row_reduce16(float v) {
    v = dpp_add<0x108>(v);   // row_shl:8
    v = dpp_add<0x104>(v);   // row_shl:4
    v = dpp_add<0x102>(v);   // row_shl:2
    v = dpp_add<0x101>(v);   // row_shl:1
    return v;
}

// Routing math for one token given its 18 full scores (math identical to
// reference `_router`; harness-verified rounds 1, 5-9).
__device__ __forceinline__ void route_one(const float* __restrict__ s,
                                          int tok,
                                          float* __restrict__ out,
                                          unsigned int* __restrict__ lcnt)
{
    const float g0 = 1.f / (1.f + expf(-s[16]));
    const float g1 = 1.f / (1.f + expf(-s[17]));

    // --- Group A: experts 0..7, top-1 of softmax ---
    int aidx = 0; float amax = s[0];
#pragma unroll
    for (int i = 1; i < 8; ++i)
        if (s[i] > amax) { amax = s[i]; aidx = i; }
    float asum = 0.f;
#pragma unroll
    for (int i = 0; i < 8; ++i) asum += expf(s[i] - amax);
    const float a_best = 1.f / asum;

    // --- Group B: experts 8..11, top-1, gated by g0 ---
    int bidx = 0; float bmax = s[8];
#pragma unroll
    for (int i = 1; i < 4; ++i)
        if (s[8 + i] > bmax) { bmax = s[8 + i]; bidx = i; }
    float bsum = 0.f;
#pragma unroll
    for (int i = 0; i < 4; ++i) bsum += expf(s[8 + i] - bmax);
    const float b_w = (g0 > 0.15f) ? ((1.f / bsum) * g0) : 0.f;

    // --- Group C: experts 12..15, top-2 of softmax, gated by g1 ---
    int c1 = 0; float cmax = s[12];
#pragma unroll
    for (int i = 1; i < 4; ++i)
        if (s[12 + i] > cmax) { cmax = s[12 + i]; c1 = i; }
    float csum = 0.f;
#pragma unroll
    for (int i = 0; i < 4; ++i) csum += expf(s[12 + i] - cmax);
    int c2 = -1; float c2v = -1e30f;
#pragma unroll
    for (int i = 0; i < 4; ++i)
        if (i != c1 && s[12 + i] > c2v) { c2v = s[12 + i]; c2 = i; }
    const float cg   = (g1 > 0.15f) ? g1 : 0.f;
    const float c_w1 = (1.f / csum) * cg;
    const float c_w2 = (expf(c2v - cmax) / csum) * cg;

    // --- normalize and write ---
    const float inv = 1.f / (a_best + b_w + c_w1 + c_w2 + 1e-8f);
    float2* ow = reinterpret_cast<float2*>(out + (size_t)tok * 6);
    ow[0] = make_float2(a_best * inv, b_w * inv);
    ow[1] = make_float2(c_w1 * inv, c_w2 * inv);
    ow[2] = make_float2(0.f, 0.f);
    float2* oi = reinterpret_cast<float2*>(out + NW6 + (size_t)tok * 6);
    oi[0] = make_float2((float)aidx, (float)(8 + bidx));
    oi[1] = make_float2((float)(12 + c1), (float)(12 + c2));
    oi[2] = make_float2(0.f, 0.f);

    atomicAdd(&lcnt[aidx], 1u);
    atomicAdd(&lcnt[8 + bidx], 1u);
    atomicAdd(&lcnt[12 + c1], 1u);
    atomicAdd(&lcnt[12 + c2], 1u);
}

// ---------------- Fused: scores over full D + routing + aux ----------------
// 1024 blocks x 16 tokens x 4 waves (4 tokens/wave, one per 16-lane group).
// D walked in 8 tiles of 256 dims. Every x DMA reads 1 KB contiguous from
// ONE token row; W pieces (18 x 1 KB) staged by wave 0, double-buffered.
// Per tile: barrier -> stage W(t+1) + issue x(t+1) -> counted vmcnt (22 for
// wave 0 / 4 for others: gates tile t's data, keeps t+1 in flight) ->
// barrier -> compute 4 chunks. x LDS padded (stride 65 f4) to spread the
// 4-way read conflict across banks.
__global__ __launch_bounds__(256, 2) void fused_router_kernel(
    const float* __restrict__ x,
    const float* __restrict__ We,
    const float* __restrict__ Wg,
    float* __restrict__ out,
    unsigned int* __restrict__ gcounts)
{
    __shared__ float4 smem[WDB + 4 * XWV];   // 70,144 B
    __shared__ unsigned int lcnt[16];

    const int tid   = threadIdx.x;
    const int strip = blockIdx.x;           // 0..1023, 16 tokens each

    const float4* __restrict__ x4  = reinterpret_cast<const float4*>(x);
    const float4* __restrict__ We4 = reinterpret_cast<const float4*>(We);
    const float4* __restrict__ Wg4 = reinterpret_cast<const float4*>(Wg);

    const int wave  = tid >> 6;             // 0..3
    const int lane  = tid & 63;
    const int l16   = lane & 15;
    const int gl    = lane >> 4;            // group = token within wave, 0..3
    const int xbase = WDB + wave * XWV;     // this wave's x ring (f4 idx)

    // Wave 0 stages ALL 18 rows of W piece p (256 dims, 1 KB/row) into
    // buffer p&1. 18 DMA instructions, each 1 KB contiguous.
    auto stage_W = [&](int p) {
#pragma unroll
        for (int e = 0; e < 18; ++e) {
            const float4* gsrc = ((e < 16) ? (We4 + (size_t)e * D4)
                                           : (Wg4 + (size_t)(e - 16) * D4))
                                 + p * 64 + lane;
            ASYNC_CP16(gsrc, smem + (p & 1) * 1152 + e * 64);
        }
    };

    // Issue tile t (this wave's 4 tokens x 256 dims) into ring slot t&1.
    // 4 instructions, each 1 KB contiguous from one token row. Dest of each
    // instruction is a contiguous 64-f4 run at padded stride 65.
    auto issue_x = [&](int t) {
#pragma unroll
        for (int tk = 0; tk < 4; ++tk) {
            const float4* gsrc = x4
                + (size_t)(strip * TPB + wave * 4 + tk) * D4 + t * 64 + lane;
            ASYNC_CP16(gsrc, smem + xbase + (t & 1) * XSLOT + tk * XSTR);
        }
    };

    float a[18];
#pragma unroll
    for (int e = 0; e < 18; ++e) a[e] = 0.f;

    // Compute 64-dim chunk ch of tile t. Group gl's lane l16 covers 4 dims
    // of token gl; 18 broadcast W reads (4-way same-address = free).
    auto compute = [&](int t, int ch) {
        const float4 xv = smem[xbase + (t & 1) * XSLOT + gl * XSTR
                               + ch * 16 + l16];
        const float4* wb = smem + (t & 1) * 1152 + ch * 16 + l16;
#pragma unroll
        for (int e = 0; e < 18; ++e)
            a[e] += DOT4(wb[e * 64], xv);
    };

    // ---- prologue: W pieces 0,1 + x tiles 0,1; full drain ----
    if (wave == 0) stage_W(0);
    issue_x(0);
    if (wave == 0) stage_W(1);
    issue_x(1);
    if (tid < 16) lcnt[tid] = 0u;
    __syncthreads();                    // vmcnt(0): W0,W1,x0,x1 resident

    for (int t = 0; t < 8; ++t) {
        if (t) {
            __builtin_amdgcn_s_barrier();   // all waves done with tile t-1
            if (t < 7) {
                if (wave == 0) stage_W(t + 1);  // buf (t+1)&1: freed by t-1
                issue_x(t + 1);                 // slot (t+1)&1: freed by t-1
                // Gate tile t's data; leave tile t+1 (22 or 4 ops) in flight.
                if (wave == 0) waitv<22>(); else waitv<4>();
            } else {
                waitv<0>();                     // tail: drain W7 + x7
            }
            __builtin_amdgcn_s_barrier();       // W(t) visible to all waves
        }
#pragma unroll
        for (int ch = 0; ch < 4; ++ch) compute(t, ch);
    }

    // ---- reduce 18 sums across each 16-lane group (pure VALU) ----
#pragma unroll
    for (int e = 0; e < 18; ++e) a[e] = row_reduce16(a[e]);

    // ---- routing: lane 0 of each group handles its 1 token ----
    if (l16 == 0) {
        const int tok = strip * TPB + wave * 4 + gl;
        route_one(a, tok, out, lcnt);
    }

    __syncthreads();
    if (tid < 16) {
        const unsigned int c = lcnt[tid];
        if (c) atomicAdd(&gcounts[tid], c);
    }
    __syncthreads();

    // Last-block ticket: aux loss. Reference bincount counts the 2 zero-pad
    // indices per token -> expert 0 gets +2*NTOK; total = 6*NTOK.
    if (tid == 0) {
        __threadfence();
        const unsigned int t = atomicAdd(&gcounts[16], 1u);
        if (t == gridDim.x - 1) {
            const float total = 6.0f * (float)NTOK;
            const float uni = 1.0f / 16.0f;
            float aux = 0.f;
            for (int e = 0; e < 16; ++e) {
                float c = (float)atomicAdd(&gcounts[e], 0u)
                          + (e == 0 ? 2.0f * (float)NTOK : 0.0f);
                aux += uni * (logf(uni) - logf(c / total));
            }
            out[2 * NW6] = aux * 0.01f;
        }
    }
}

extern "C" void kernel_launch(void* const* d_in, const int* in_sizes, int n_in,
                              void* d_out, int out_size, void* d_ws, size_t ws_size,
                              hipStream_t stream)
{
    const float* x  = (const float*)d_in[0];   // (4,4096,2048)
    const float* We = (const float*)d_in[1];   // (16,2048)
    const float* Wg = (const float*)d_in[2];   // (2,2048)
    float* out = (float*)d_out;

    unsigned int* counts = (unsigned int*)d_ws;

    hipMemsetAsync(counts, 0, 17 * sizeof(unsigned int), stream);

    // Single fused kernel: 1024 strips of 16 tokens, 4 waves each.
    fused_router_kernel<<<dim3(NBLK), 256, 0, stream>>>(x, We, Wg, out, counts);
}